// Round 6
// baseline (256.528 us; speedup 1.0000x reference)
//
#include <hip/hip_runtime.h>

// ---------------------------------------------------------------------------
// SelfAttention: out = softmax((x@Wk+bk) @ (x@Wq+bq)^T) @ (x@Wv+bv)
// B=4, N=2048, E=A=1024, fp32 in/out.
// R14: memory-kernel coalescing/overhead fixes (GEMMs untouched from R13):
//  - prep W-transpose: 64x64 fp16 tiles (128B coalesced read+write; was 32x32
//    with 64B strided writes). pad-76 LDS stride keeps ushort4 8B-aligned.
//  - softmax: one WAVE per row (2048 blocks, 4 rows/block, no barriers,
//    shfl-only reduce, 8x float4 per lane). Sum order changes -> P last-ulp.
//  - v->vT backfill tiles in scores_vT: 64x64 (128B both directions).
//  - proj/scores/PV GEMMs, XCD remap, grids: unchanged (absmax ~0.081).
// ---------------------------------------------------------------------------

typedef __attribute__((ext_vector_type(8))) _Float16 half8;   // 4 VGPRs
typedef __attribute__((ext_vector_type(4))) float floatx4;

#define BK 64
#define MFMA16 __builtin_amdgcn_mfma_f32_16x16x32_f16

static __device__ __forceinline__ unsigned short f2h(float f) {
    _Float16 h = (_Float16)f;          // RNE
    return *(unsigned short*)&h;
}

// async global->LDS, 16B per lane; LDS dst = wave-uniform base + lane*16
static __device__ __forceinline__ void gll16(const unsigned short* g,
                                             unsigned short* l) {
    __builtin_amdgcn_global_load_lds(
        (__attribute__((address_space(1))) void*)(g),
        (__attribute__((address_space(3))) void*)(l), 16, 0, 0);
}

// XCD-chunked bijective remap (m157; requires nwg % 8 == 0).
static __device__ __forceinline__ void xcd_remap(int& bx, int& by, int& bz) {
    const int gx = gridDim.x, gy = gridDim.y, gz = gridDim.z;
    const int flat = blockIdx.x + gx * (blockIdx.y + gy * blockIdx.z);
    const int w = (flat & 7) * ((gx * gy * gz) >> 3) + (flat >> 3);
    bx = w % gx;
    const int r = w / gx;
    by = r % gy;
    bz = r / gy;
}

// ---------------------------------------------------------------------------
// prep: blocks 0..8191 cast x -> fp16;
//       8192..8959: 64x64 W-transpose tiles (256 per W, 3 Ws) -> WT fp16;
//       8960..8971: bias concat (12 blocks x 256 = 3072).
// ---------------------------------------------------------------------------
__global__ __launch_bounds__(256)
void prep(const float* __restrict__ x,
          const float* __restrict__ W0, const float* __restrict__ W1,
          const float* __restrict__ W2,
          const float* __restrict__ b0, const float* __restrict__ b1,
          const float* __restrict__ b2,
          unsigned short* __restrict__ x16, unsigned short* __restrict__ WT,
          float* __restrict__ bias3) {
    __shared__ unsigned short wtile[64][76];   // pad 76: 152B row, 8B-aligned
    const int bid = blockIdx.x;
    const int tid = threadIdx.x;
    if (bid < 8192) {
        int i = bid * 1024 + tid * 4;
        float4 f = *(const float4*)(x + i);
        *(ushort4*)(x16 + i) =
            make_ushort4(f2h(f.x), f2h(f.y), f2h(f.z), f2h(f.w));
    } else if (bid < 8960) {
        int wz = bid - 8192;
        int z = wz >> 8;                     // which W (256 tiles each)
        int t = wz & 255;
        const float* W = z == 0 ? W0 : (z == 1 ? W1 : W2);
        unsigned short* Tz = WT + (size_t)z * 1024 * 1024;
        int c0 = (t & 15) * 64, r0 = (t >> 4) * 64;
        int tx = tid & 15, ty = tid >> 4;
#pragma unroll
        for (int j = 0; j < 4; ++j) {
            int r = ty + j * 16;
            float4 f = *(const float4*)(W + (r0 + r) * 1024 + c0 + tx * 4);
            *(ushort4*)&wtile[r][tx * 4] =
                make_ushort4(f2h(f.x), f2h(f.y), f2h(f.z), f2h(f.w));
        }
        __syncthreads();
#pragma unroll
        for (int j = 0; j < 4; ++j) {
            int a = ty + j * 16;
            ushort4 u = make_ushort4(wtile[tx * 4 + 0][a], wtile[tx * 4 + 1][a],
                                     wtile[tx * 4 + 2][a], wtile[tx * 4 + 3][a]);
            *(ushort4*)(Tz + (size_t)(c0 + a) * 1024 + r0 + tx * 4) = u;
        }
    } else {
        int i = (bid - 8960) * 256 + tid;    // 12*256 = 3072
        int s = i >> 10;
        const float* b = s == 0 ? b0 : (s == 1 ? b1 : b2);
        bias3[i] = b[i & 1023];
    }
}

// ---------------------------------------------------------------------------
// NT GEMM body (R11 structure, 2-barrier single-buffer, verified 36% Mfma):
// C[M,N] = A[M,K]*B[N,K]^T (+bias[col]); fp16 in, fp32 acc.
// Block TM x TN, 256 threads (4 waves 2x2; wave tile TM/2 x TN/2), BK=64.
// LDS: unpadded [row][64]; XOR chunk swizzle (pos p of row r holds chunk
// p ^ (r&7)) — conflict-free (rocprof 0 across R8-R13).
// mode 0: fp32 -> Cf; mode 2: fp16 segmented -> Ch (k|q|v contiguous).
// ---------------------------------------------------------------------------
template <int TM, int TN>
static __device__ __forceinline__ void gemm_body(
    unsigned short* smem, int bx, int by, int bz,
    const unsigned short* __restrict__ A,
    const unsigned short* __restrict__ B,
    const float* __restrict__ bias,
    float* __restrict__ Cf, unsigned short* __restrict__ Ch,
    int mode, int N, int K, long long sA, long long sB, long long sC) {
    constexpr int WM = TM / 2;       // wave tile rows
    constexpr int MI = WM / 16;      // acc row-tiles per wave
    constexpr int WN = TN / 2;
    constexpr int NI = WN / 16;      // acc col-tiles per wave
    unsigned short* As = smem;                  // TM x BK
    unsigned short* Bs = smem + TM * BK;        // TN x BK

    const int tid = threadIdx.x;
    const int lane = tid & 63;
    const int wave = tid >> 6;          // 0..3
    const int quad = lane >> 4;
    const int l15 = lane & 15;
    const int wm = (wave & 1) * WM;
    const int wn = (wave >> 1) * WN;

    const long long zA = (long long)bz * sA;
    const long long zB = (long long)bz * sB;
    const long long zC = (long long)bz * sC;
    const int m0 = by * TM;
    const int n0 = bx * TN;

    // staging: lane i covers row i>>3; position p=i&7 gets chunk p ^ (row&7)
    const int arow = wave * (TM / 4) + (lane >> 3);
    const int brow = wave * (TN / 4) + (lane >> 3);
    const int schunk8 = (((lane & 7) ^ ((lane >> 3) & 7)) << 3);
    const long long aoff = zA + (long long)(m0 + arow) * K + schunk8;
    const long long boff = zB + (long long)(n0 + brow) * K + schunk8;
    unsigned short* lA = As + (wave * (TM / 4)) * BK;
    unsigned short* lB = Bs + (wave * (TN / 4)) * BK;

    floatx4 zero = {0.f, 0.f, 0.f, 0.f};
    floatx4 acc[MI][NI];
#pragma unroll
    for (int i = 0; i < MI; ++i)
#pragma unroll
        for (int j = 0; j < NI; ++j) acc[i][j] = zero;

    for (int k0 = 0; k0 < K; k0 += BK) {
        __syncthreads();
#pragma unroll
        for (int j = 0; j < TM / 32; ++j)
            gll16(A + aoff + k0 + (long long)j * 8 * K, lA + j * 8 * BK);
#pragma unroll
        for (int j = 0; j < TN / 32; ++j)
            gll16(B + boff + k0 + (long long)j * 8 * K, lB + j * 8 * BK);
        __syncthreads();

#pragma unroll
        for (int t = 0; t < 2; ++t) {      // two K=32 MFMA steps per BK=64
            half8 a[MI], b[NI];
#pragma unroll
            for (int mi = 0; mi < MI; ++mi) {
                int r = wm + mi * 16 + l15;
                int p = (t * 4 + quad) ^ (r & 7);
                a[mi] = *(const half8*)&As[r * BK + p * 8];
            }
#pragma unroll
            for (int ni = 0; ni < NI; ++ni) {
                int r = wn + ni * 16 + l15;
                int p = (t * 4 + quad) ^ (r & 7);
                b[ni] = *(const half8*)&Bs[r * BK + p * 8];
            }
#pragma unroll
            for (int mi = 0; mi < MI; ++mi)
#pragma unroll
                for (int ni = 0; ni < NI; ++ni)
                    acc[mi][ni] = MFMA16(a[mi], b[ni], acc[mi][ni], 0, 0, 0);
        }
    }

    // epilogue: C/D layout col=lane&15, row=quad*4+reg  [verified m89/m91]
#pragma unroll
    for (int mi = 0; mi < MI; ++mi)
#pragma unroll
        for (int ni = 0; ni < NI; ++ni) {
            int colg = n0 + wn + ni * 16 + l15;
            float bv = bias ? bias[colg] : 0.f;
#pragma unroll
            for (int r = 0; r < 4; ++r) {
                int rowg = m0 + wm + mi * 16 + quad * 4 + r;
                float v = acc[mi][ni][r] + bv;
                if (mode == 0) {
                    Cf[zC + (long long)rowg * N + colg] = v;
                } else {  // mode 2: segmented fp16 (k16|q16|v16 contiguous)
                    int seg = colg >> 10;
                    Ch[(long long)seg * sC + (long long)rowg * 1024 +
                       (colg & 1023)] = f2h(v);
                }
            }
        }
}

// plain GEMM kernel (proj, PV): m157 XCD remap + body
template <int TM, int TN>
__global__ __launch_bounds__(256, 2)
void gemm_nt(const unsigned short* __restrict__ A,
             const unsigned short* __restrict__ B,
             const float* __restrict__ bias,
             float* __restrict__ Cf,
             unsigned short* __restrict__ Ch,
             int mode, int N, int K,
             long long sA, long long sB, long long sC) {
    __shared__ unsigned short smem[(TM + TN) * BK];
    int bx, by, bz;
    xcd_remap(bx, by, bz);
    gemm_body<TM, TN>(smem, bx, by, bz, A, B, bias, Cf, Ch, mode, N, K,
                      sA, sB, sC);
}

// ---------------------------------------------------------------------------
// scores + vT dispatch: 3072 blocks. Physical block f -> XCD c = f&7,
// rank = f>>3. rank<128: scores GEMM block (XCD-chunked, w = c*128+rank over
// the (16,16,4) grid). rank>=128: one 64x64 v16->vT transpose tile (2048
// tiles total; 128B-coalesced both directions) backfilling scores' tail.
// ---------------------------------------------------------------------------
__global__ __launch_bounds__(256, 2)
void scores_vT(const unsigned short* __restrict__ k16,
               const unsigned short* __restrict__ q16,
               float* __restrict__ S,
               const unsigned short* __restrict__ v,
               unsigned short* __restrict__ vT) {
    __shared__ unsigned short smem[(128 + 128) * BK];   // 32KB
    const int f = blockIdx.x;
    const int c = f & 7;
    const int rank = f >> 3;
    if (rank < 128) {
        const int w = c * 128 + rank;          // scores work id, XCD-chunked
        const int bx = w & 15;
        const int by = (w >> 4) & 15;
        const int bz = w >> 8;
        gemm_body<128, 128>(smem, bx, by, bz, k16, q16, nullptr, S, nullptr,
                            0, 2048, 1024,
                            (long long)2048 * 1024, (long long)2048 * 1024,
                            (long long)2048 * 2048);
    } else {
        // 64x64 transpose tile: t in [0,2048); 512 tiles per batch
        const int t = c * 256 + (rank - 128);
        auto tile = (unsigned short(*)[76])smem;   // 64x76 ushort = 9728B
        const int tid = threadIdx.x;
        int z = t >> 9;                  // batch
        int rest = t & 511;              // 16 a-tiles x 32 n-tiles
        int c0 = (rest & 15) * 64;       // a base
        int r0 = (rest >> 4) * 64;       // n base
        long long zs = (long long)z * 2048 * 1024;
        int tx = tid & 15, ty = tid >> 4;
#pragma unroll
        for (int j = 0; j < 4; ++j) {
            int r = ty + j * 16;
            ushort4 u = *(const ushort4*)(v + zs +
                                          (long long)(r0 + r) * 1024 + c0 + tx * 4);
            *(ushort4*)&tile[r][tx * 4] = u;
        }
        __syncthreads();
#pragma unroll
        for (int j = 0; j < 4; ++j) {
            int a = ty + j * 16;
            ushort4 u = make_ushort4(tile[tx * 4 + 0][a], tile[tx * 4 + 1][a],
                                     tile[tx * 4 + 2][a], tile[tx * 4 + 3][a]);
            *(ushort4*)(vT + zs + (long long)(c0 + a) * 2048 + r0 + tx * 4) = u;
        }
    }
}

// ---------------------------------------------------------------------------
// row softmax, one WAVE per row: scores fp32 [8192][2048] -> attn fp16.
// 2048 blocks x 4 waves; no __syncthreads; shfl-only reduce; 8x float4/lane.
// ---------------------------------------------------------------------------
__global__ __launch_bounds__(256)
void softmax_rows(const float* __restrict__ S, unsigned short* __restrict__ P) {
    const int tid = threadIdx.x;
    const int lane = tid & 63;
    const int wave = tid >> 6;
    const long long row = (long long)blockIdx.x * 4 + wave;
    const float* s = S + row * 2048;
    unsigned short* p = P + row * 2048;

    float vals[32];
#pragma unroll
    for (int j = 0; j < 8; ++j) {
        float4 f = *(const float4*)(s + j * 256 + lane * 4);
        vals[j * 4 + 0] = f.x; vals[j * 4 + 1] = f.y;
        vals[j * 4 + 2] = f.z; vals[j * 4 + 3] = f.w;
    }

    float m = vals[0];
#pragma unroll
    for (int i = 1; i < 32; ++i) m = fmaxf(m, vals[i]);
#pragma unroll
    for (int off = 32; off >= 1; off >>= 1) m = fmaxf(m, __shfl_xor(m, off));

    float sum = 0.f;
#pragma unroll
    for (int i = 0; i < 32; ++i) {
        vals[i] = __expf(vals[i] - m);
        sum += vals[i];
    }
#pragma unroll
    for (int off = 32; off >= 1; off >>= 1) sum += __shfl_xor(sum, off);
    float inv = 1.0f / sum;

#pragma unroll
    for (int j = 0; j < 8; ++j) {
        ushort4 ob = make_ushort4(f2h(vals[j * 4 + 0] * inv),
                                  f2h(vals[j * 4 + 1] * inv),
                                  f2h(vals[j * 4 + 2] * inv),
                                  f2h(vals[j * 4 + 3] * inv));
        *(ushort4*)(p + j * 256 + lane * 4) = ob;
    }
}

// ---------------------------------------------------------------------------
extern "C" void kernel_launch(void* const* d_in, const int* in_sizes, int n_in,
                              void* d_out, int out_size, void* d_ws,
                              size_t ws_size, hipStream_t stream) {
    const float* x  = (const float*)d_in[0];
    const float* Wk = (const float*)d_in[1];
    const float* bk = (const float*)d_in[2];
    const float* Wq = (const float*)d_in[3];
    const float* bq = (const float*)d_in[4];
    const float* Wv = (const float*)d_in[5];
    const float* bv = (const float*)d_in[6];
    float* out = (float*)d_out;

    const int Bb = 4, Ns = 2048, E = 1024, Aa = 1024;
    const int M = Bb * Ns;  // 8192

    char* p = (char*)d_ws;
    auto alloc = [&](size_t bytes) {
        char* r = p;
        p += (bytes + 255) & ~(size_t)255;
        return r;
    };
    const size_t MA = (size_t)M * Aa;          // 8.39M elems
    unsigned short* x16 = (unsigned short*)alloc(MA * 2);
    unsigned short* WT  = (unsigned short*)alloc((size_t)3 * E * Aa * 2);
    // k16,q16,v16 MUST be contiguous (segmented epilogue): MA*2 is a
    // multiple of 256, so alloc() inserts no padding.
    unsigned short* k16 = (unsigned short*)alloc(MA * 2);
    unsigned short* q16 = (unsigned short*)alloc(MA * 2);
    unsigned short* v16 = (unsigned short*)alloc(MA * 2);
    unsigned short* vT  = (unsigned short*)alloc(MA * 2);
    unsigned short* attn = (unsigned short*)alloc((size_t)M * Ns * 2);
    float* bias3 = (float*)alloc(3072 * 4);
    float* scores = (float*)alloc((size_t)Bb * Ns * Ns * 4);

    // 1. prep: x->fp16, W^T x3 (64x64 tiles), bias concat (one dispatch)
    prep<<<8972, 256, 0, stream>>>(x, Wk, Wq, Wv, bk, bq, bv, x16, WT, bias3);

    // 2. fused projections: [k|q|v] = x16 @ [Wk|Wq|Wv]^T + bias3
    //    grid 24 x 64 = 1536 blocks (~5/CU, at the residency knee)
    gemm_nt<128, 128><<<dim3(3 * Aa / 128, M / 128, 1), 256, 0, stream>>>(
        x16, WT, bias3, nullptr, k16, 2, 3 * Aa, E, 0, 0, (long long)MA);

    // 3. scores (1024 XCD-chunked GEMM blocks) + v->vT (2048 64x64 tiles)
    scores_vT<<<3072, 256, 0, stream>>>(k16, q16, scores, v16, vT);

    // 4. softmax rows -> fp16 attn (wave-per-row, no barriers)
    softmax_rows<<<2048, 256, 0, stream>>>(scores, attn);

    // 5. out[b,n,a] = sum_m attn[b,n,m] * vT[b,a,m]
    //    TN=64: grid 16x16x4 = 1024 blocks, residency 6 blocks/CU
    gemm_nt<128, 64><<<dim3(Aa / 64, Ns / 128, Bb), 256, 0, stream>>>(
        attn, vT, nullptr, out, nullptr, 0, Aa, Ns,
        (long long)Ns * Ns, (long long)Aa * Ns, (long long)Ns * Aa);
}